// Round 15
// baseline (143.173 us; speedup 1.0000x reference)
//
#include <hip/hip_runtime.h>
#include <hip/hip_bf16.h>
#include <hip/hip_fp16.h>
#include <math.h>

#define BATCH   2
#define SEQ     4096
#define DIM     1024
#define HEADS   16
#define DSTATE  64
#define HEADDIM 64
#define BLOCKL  64
#define NCHUNK  64
#define ROWS    (BATCH*SEQ)

typedef __attribute__((ext_vector_type(4))) float f32x4;
typedef __attribute__((ext_vector_type(8))) short bf16x8;
typedef __attribute__((ext_vector_type(8))) _Float16 f16x8;

static __device__ __forceinline__ float softplus_f(float x){
    return (x > 20.f) ? x : log1pf(__expf(x));
}
static __device__ __forceinline__ ushort f2b(float f){
    __hip_bfloat16 h = __float2bfloat16(f);
    return *reinterpret_cast<ushort*>(&h);
}
static __device__ __forceinline__ float b2f(ushort u){
    uint x = ((uint)u) << 16;
    return *reinterpret_cast<float*>(&x);
}
static __device__ __forceinline__ void gload16(const void* g, void* l){
    __builtin_amdgcn_global_load_lds((const __attribute__((address_space(1))) unsigned int*)g,
                                     (__attribute__((address_space(3))) unsigned int*)l, 16, 0, 0);
}

// ---------------------------------------------------------------------------
// K1 (merged): blocks [0,ROWS): dt per row (TRANSPOSED layout dt_t[b*16+h][s]).
// blocks [ROWS,ROWS+256): Wt[n][k] = bf16(W_out[k][n])     (verified round 14)
__global__ __launch_bounds__(256) void k_dtwt(const float* __restrict__ X,
        const float* __restrict__ Wdt, const float* __restrict__ dtb,
        const float* __restrict__ W,
        float* __restrict__ dt_t, ushort* __restrict__ Wt){
    __shared__ float xrow[DIM];
    __shared__ float red[16][17];
    __shared__ float t[64][65];
    int bidx = blockIdx.x;
    int tid = threadIdx.x;
    if (bidx < ROWS){
        int r = bidx;
        int b = r >> 12;
        int s = r & (SEQ-1);
        *(f32x4*)(xrow + tid*4) = *(const f32x4*)(X + (size_t)r*DIM + tid*4);
        __syncthreads();
        int part = tid >> 4, h = tid & 15;
        int d0 = part * 64;
        float acc = 0.f;
        #pragma unroll 8
        for (int i = 0; i < 64; ++i)
            acc += xrow[d0 + i] * Wdt[(size_t)(d0 + i)*HEADS + h];
        red[part][h] = acc;
        __syncthreads();
        if (tid < 16){
            float sum = 0.f;
            #pragma unroll
            for (int p = 0; p < 16; ++p) sum += red[p][tid];
            sum += dtb[(size_t)s*HEADS + tid];
            float dtv = softplus_f(sum);
            dt_t[(size_t)(b*HEADS + tid)*SEQ + s] = dtv;
        }
    } else {
        int bid = bidx - ROWS;
        int kt = bid >> 4, nt = bid & 15;
        int lr = tid >> 4, lc4 = (tid & 15) * 4;
        #pragma unroll
        for (int q = 0; q < 4; ++q){
            int k = lr + q*16;
            *(f32x4*)&t[k][lc4] = *(const f32x4*)(W + (size_t)(kt*64 + k)*DIM + nt*64 + lc4);
        }
        __syncthreads();
        #pragma unroll
        for (int q = 0; q < 4; ++q){
            int n = lr + q*16;
            ushort o[4];
            #pragma unroll
            for (int j = 0; j < 4; ++j) o[j] = f2b(t[lc4+j][n]);
            *(short4*)(Wt + (size_t)(nt*64 + n)*DIM + kt*64 + lc4) = *(short4*)&o[0];
        }
    }
}

// ---------------------------------------------------------------------------
// K2 (MFMA): G=C·B^T -> M(bf16) ; state = Xd^T·(w·B) ; Y_diag=M·Xd (bf16 out)
// LDS 18 KB, triple-overlaid; per-wave redundant scan.   (verified round 14)
__global__ __launch_bounds__(256) void k_chunk(const float* __restrict__ X,
        const float* __restrict__ Bin, const float* __restrict__ Cin,
        const float* __restrict__ dt_t, const float* __restrict__ alog,
        ushort* __restrict__ ybf, ushort* __restrict__ cstate, float* __restrict__ css_g){
    int bid = blockIdx.x;                  // ((b*64+c)*16+h)
    int h = bid & 15, c = (bid >> 4) & 63, b = bid >> 10;
    int tid = threadIdx.x;
    int lane = tid & 63, wave = tid >> 6;
    int r0 = b*SEQ + c*BLOCKL;

    __shared__ __align__(16) char region0[18432];
    ushort* Cs  = (ushort*)region0;            // ph1 [64][72]
    ushort* Bs  = (ushort*)(region0 + 9216);   // ph1 [64][72]
    ushort* XdT = (ushort*)region0;            // ph2/3 (over Cs)
    ushort* WBT = (ushort*)(region0 + 9216);   // ph2   (over Bs)
    ushort* Mb  = (ushort*)(region0 + 9216);   // ph3   (over WBT)

    int l  = tid >> 2;
    int c0 = (tid & 3) * 16;

    f32x4 xr[4], br[4], cr[4];
    {
        const float* xp = X   + (size_t)(r0 + l)*DIM + h*HEADDIM + c0;
        const float* bp = Bin + (size_t)(r0 + l)*DIM + h*DSTATE  + c0;
        const float* cp = Cin + (size_t)(r0 + l)*DIM + h*DSTATE  + c0;
        #pragma unroll
        for (int q = 0; q < 4; ++q){
            xr[q] = *(const f32x4*)(xp + q*4);
            br[q] = *(const f32x4*)(bp + q*4);
            cr[q] = *(const f32x4*)(cp + q*4);
        }
    }
    float dt_l = dt_t[(size_t)(b*HEADS + h)*SEQ + c*BLOCKL + lane];
    float a    = -__expf(alog[h]) * dt_l;
    #pragma unroll
    for (int off = 1; off < 64; off <<= 1){
        float v = __shfl_up(a, off, 64);
        if (lane >= off) a += v;
    }
    float cs63 = __shfl(a, 63, 64);
    float w_l  = __expf(cs63 - a);
    if (tid < 64) css_g[(size_t)bid*64 + tid] = a;

    {
        ushort tc[16], tb[16];
        #pragma unroll
        for (int q = 0; q < 4; ++q)
            #pragma unroll
            for (int j = 0; j < 4; ++j){
                tc[q*4+j] = f2b(cr[q][j]);
                tb[q*4+j] = f2b(br[q][j]);
            }
        *(uint4*)&Cs[l*72 + c0]     = *(uint4*)&tc[0];
        *(uint4*)&Cs[l*72 + c0 + 8] = *(uint4*)&tc[8];
        *(uint4*)&Bs[l*72 + c0]     = *(uint4*)&tb[0];
        *(uint4*)&Bs[l*72 + c0 + 8] = *(uint4*)&tb[8];
    }
    __syncthreads();            // [sync1]

    int cl15  = lane & 15;
    int g     = lane >> 4;
    int arow  = wave*16 + cl15;
    int kof   = g * 8;
    int rbase = wave*16 + g*4;

    f32x4 gacc[4];
    #pragma unroll
    for (int j = 0; j < 4; ++j) gacc[j] = (f32x4){0.f,0.f,0.f,0.f};
    #pragma unroll
    for (int k = 0; k < 2; ++k){
        bf16x8 aa = *(const bf16x8*)&Cs[arow*72 + k*32 + kof];
        #pragma unroll
        for (int j = 0; j < 4; ++j){
            bf16x8 bb = *(const bf16x8*)&Bs[(16*j + cl15)*72 + k*32 + kof];
            gacc[j] = __builtin_amdgcn_mfma_f32_16x16x32_bf16(aa, bb, gacc[j], 0, 0, 0);
        }
    }
    __syncthreads();            // [sync2]

    {
        float dl = __shfl(dt_l, l, 64);
        float wl = __shfl(w_l,  l, 64);
        #pragma unroll
        for (int q = 0; q < 4; ++q)
            #pragma unroll
            for (int j = 0; j < 4; ++j){
                int p = c0 + q*4 + j;
                XdT[p*72 + l] = f2b(xr[q][j] * dl);
                WBT[p*72 + l] = f2b(br[q][j] * wl);
            }
    }
    __syncthreads();            // [sync3]

    f32x4 st[4];
    #pragma unroll
    for (int j = 0; j < 4; ++j) st[j] = (f32x4){0.f,0.f,0.f,0.f};
    #pragma unroll
    for (int k = 0; k < 2; ++k){
        bf16x8 aw = *(const bf16x8*)&XdT[arow*72 + k*32 + kof];
        #pragma unroll
        for (int j = 0; j < 4; ++j){
            bf16x8 bb = *(const bf16x8*)&WBT[(16*j + cl15)*72 + k*32 + kof];
            st[j] = __builtin_amdgcn_mfma_f32_16x16x32_bf16(aw, bb, st[j], 0, 0, 0);
        }
    }
    #pragma unroll
    for (int j = 0; j < 4; ++j)
        #pragma unroll
        for (int r = 0; r < 4; ++r){
            __half hv = __float2half(st[j][r]);
            cstate[(size_t)bid*4096 + (size_t)(rbase + r)*64 + 16*j + cl15] = *(ushort*)&hv;
        }

    float mreg[4][4];
    {
        float csr[4], csc[4];
        #pragma unroll
        for (int r = 0; r < 4; ++r) csr[r] = __shfl(a, rbase + r, 64);
        #pragma unroll
        for (int j = 0; j < 4; ++j) csc[j] = __shfl(a, 16*j + cl15, 64);
        #pragma unroll
        for (int j = 0; j < 4; ++j)
            #pragma unroll
            for (int r = 0; r < 4; ++r){
                int row = rbase + r, col = 16*j + cl15;
                mreg[j][r] = (col <= row) ? gacc[j][r]*__expf(csr[r] - csc[j]) : 0.f;
            }
    }
    __syncthreads();            // [sync4]

    #pragma unroll
    for (int j = 0; j < 4; ++j)
        #pragma unroll
        for (int r = 0; r < 4; ++r)
            Mb[(rbase + r)*72 + 16*j + cl15] = f2b(mreg[j][r]);
    __syncthreads();            // [sync5]

    f32x4 y[4];
    #pragma unroll
    for (int j = 0; j < 4; ++j) y[j] = (f32x4){0.f,0.f,0.f,0.f};
    #pragma unroll
    for (int k = 0; k < 2; ++k){
        bf16x8 am = *(const bf16x8*)&Mb[arow*72 + k*32 + kof];
        #pragma unroll
        for (int j = 0; j < 4; ++j){
            bf16x8 bx = *(const bf16x8*)&XdT[(16*j + cl15)*72 + k*32 + kof];
            y[j] = __builtin_amdgcn_mfma_f32_16x16x32_bf16(am, bx, y[j], 0, 0, 0);
        }
    }
    #pragma unroll
    for (int j = 0; j < 4; ++j)
        #pragma unroll
        for (int r = 0; r < 4; ++r)
            ybf[(size_t)(r0 + rbase + r)*DIM + h*HEADDIM + 16*j + cl15] = f2b(y[j][r]);
}

// ---------------------------------------------------------------------------
// K3: inter-chunk scan. Decay factors preloaded to LDS; prefetch depth 2.
__global__ __launch_bounds__(256) void k_scan(ushort* __restrict__ cstate,
        const float* __restrict__ css_g, float* __restrict__ fs_out){
    int bid = blockIdx.x;                  // b(2) * h(16) * tile(8)
    int tile = bid & 7, hh = (bid >> 3) & 15, b = bid >> 7;
    int tid = threadIdx.x;
    int pn = tile*512 + tid*2;
    size_t base0 = (size_t)(b*NCHUNK)*HEADS + hh;
    __shared__ float esh[64];
    if (tid < 64)
        esh[tid] = __expf(css_g[(base0 + (size_t)tid*HEADS)*64 + 63]);
    __syncthreads();
    ushort* p0 = cstate + base0*4096 + pn;
    const size_t cstep = (size_t)HEADS*4096;
    float P0 = 0.f, P1 = 0.f;
    __half2 cur = *(const __half2*)p0;
    __half2 nxt = *(const __half2*)(p0 + cstep);
    for (int c = 0; c < NCHUNK; ++c){
        __half2 fut = nxt;
        if (c + 2 < NCHUNK) fut = *(const __half2*)(p0 + (size_t)(c+2)*cstep);
        *( __half2*)(p0 + (size_t)c*cstep) = __floats2half2_rn(P0, P1);
        float2 cf = __half22float2(cur);
        float e = esh[c];
        P0 = e*P0 + cf.x;
        P1 = e*P1 + cf.y;
        cur = nxt;
        nxt = fut;
    }
    *(float2*)&fs_out[(size_t)(b*HEADS + hh)*4096 + pn] = make_float2(P0, P1);
}

// ---------------------------------------------------------------------------
// K4 (f16 MFMA): y += exp(cs[l]) * C·S^T  (bf16 RMW)   (verified round 10/14)
__global__ __launch_bounds__(256) void k_yoff(const float* __restrict__ Cin,
        const ushort* __restrict__ cstate, const float* __restrict__ css_g,
        ushort* __restrict__ ybf){
    int bid = blockIdx.x;
    int h = bid & 15, c = (bid >> 4) & 63, b = bid >> 10;
    int tid = threadIdx.x;
    int lane = tid & 63, wave = tid >> 6;
    int r0 = b*SEQ + c*BLOCKL;
    __shared__ __align__(16) ushort Cs[64*72];
    __shared__ __align__(16) ushort Ss[64*72];
    __shared__ float cse[64];
    {
        int l  = tid >> 2;
        int c0 = (tid & 3) * 16;
        const float* cp = Cin + (size_t)(r0 + l)*DIM + h*DSTATE + c0;
        ushort tc[16];
        #pragma unroll
        for (int q = 0; q < 4; ++q){
            f32x4 vc = *(const f32x4*)(cp + q*4);
            #pragma unroll
            for (int j = 0; j < 4; ++j){
                __half hv = __float2half(vc[j]);
                tc[q*4+j] = *(ushort*)&hv;
            }
        }
        *(uint4*)&Cs[l*72 + c0]     = *(uint4*)&tc[0];
        *(uint4*)&Cs[l*72 + c0 + 8] = *(uint4*)&tc[8];
        const ushort* sp = cstate + (size_t)bid*4096 + (size_t)l*64 + c0;
        *(uint4*)&Ss[l*72 + c0]     = *(const uint4*)sp;
        *(uint4*)&Ss[l*72 + c0 + 8] = *(const uint4*)(sp + 8);
    }
    if (tid < 64) cse[tid] = __expf(css_g[(size_t)bid*64 + tid]);
    __syncthreads();

    int cl15 = lane & 15;
    int g    = lane >> 4;
    int arow = wave*16 + cl15;
    int kof  = g * 8;
    f32x4 acc[4];
    #pragma unroll
    for (int j = 0; j < 4; ++j) acc[j] = (f32x4){0.f,0.f,0.f,0.f};
    #pragma unroll
    for (int k = 0; k < 2; ++k){
        f16x8 a = *(const f16x8*)&Cs[arow*72 + k*32 + kof];
        #pragma unroll
        for (int j = 0; j < 4; ++j){
            f16x8 bb = *(const f16x8*)&Ss[(16*j + cl15)*72 + k*32 + kof];
            acc[j] = __builtin_amdgcn_mfma_f32_16x16x32_f16(a, bb, acc[j], 0, 0, 0);
        }
    }
    int rbase = wave*16 + g*4;
    #pragma unroll
    for (int j = 0; j < 4; ++j)
        #pragma unroll
        for (int r = 0; r < 4; ++r){
            float e = cse[rbase + r];
            size_t idx = (size_t)(r0 + rbase + r)*DIM + h*HEADDIM + 16*j + cl15;
            ybf[idx] = f2b(b2f(ybf[idx]) + e * acc[j][r]);
        }
}

// ---------------------------------------------------------------------------
// K5: Out = LN(y) @ Wt^T.  Self-contained (verified correct round 13), with
// the A-path SOFTWARE-PIPELINED: A regs for iter k+1 issue right after iter
// k's first barrier, so their latency hides under the 16 MFMAs.  B = gload16.
__global__ __launch_bounds__(256) void k_gemm(const ushort* __restrict__ A,
        const ushort* __restrict__ Bt, const float* __restrict__ lns,
        const float* __restrict__ lnb, float* __restrict__ Out){
    __shared__ __align__(16) ushort As[128*32];
    __shared__ __align__(16) ushort Bsh[128*32];
    __shared__ float2 mursh[128];
    __shared__ float scs[1024];
    __shared__ float bis[1024];
    int bid = blockIdx.x;
    int wgid = (bid & 7)*64 + (bid >> 3);      // XCD swizzle (512 = 8 XCD * 64)
    int bn = wgid & 7, bm = wgid >> 3;
    int tid = threadIdx.x;
    int lane = tid & 63, wave = tid >> 6;
    int wr = wave >> 1, wc = wave & 1;
    const ushort* Ag = A  + (size_t)bm*128*1024;
    const ushort* Bg = Bt + (size_t)bn*128*1024;

    // ---- pass 0: per-row LN stats over the 128 A-rows (verified round 13) --
    *(f32x4*)&scs[tid*4] = *(const f32x4*)(lns + tid*4);
    *(f32x4*)&bis[tid*4] = *(const f32x4*)(lnb + tid*4);
    {
        float ps1[8], ps2[8];
        #pragma unroll
        for (int it = 0; it < 8; ++it){
            int row = it*16 + (tid >> 4);
            const ushort* rp = Ag + (size_t)row*1024 + (tid & 15)*8;
            float s1 = 0.f, s2 = 0.f;
            #pragma unroll
            for (int q = 0; q < 8; ++q){
                uint4 v = *(const uint4*)(rp + q*128);
                const ushort* pv = (const ushort*)&v;
                #pragma unroll
                for (int e = 0; e < 8; ++e){
                    float f = b2f(pv[e]);
                    s1 += f; s2 += f*f;
                }
            }
            ps1[it] = s1; ps2[it] = s2;
        }
        #pragma unroll
        for (int it = 0; it < 8; ++it){
            #pragma unroll
            for (int m = 1; m < 16; m <<= 1){
                ps1[it] += __shfl_xor(ps1[it], m, 64);
                ps2[it] += __shfl_xor(ps2[it], m, 64);
            }
            if ((tid & 15) == 0){
                int row = it*16 + (tid >> 4);
                float mu  = ps1[it] * (1.f/DIM);
                float var = ps2[it] * (1.f/DIM) - mu*mu;
                mursh[row] = make_float2(mu, rsqrtf(var + 1e-6f));
            }
        }
    }
    __syncthreads();

    // ---- K-loop: pipelined A (regs loaded one iter ahead) -------------------
    f32x4 acc[4][4];
    #pragma unroll
    for (int i = 0; i < 4; ++i)
        #pragma unroll
        for (int j = 0; j < 4; ++j)
            acc[i][j] = (f32x4){0.f, 0.f, 0.f, 0.f};
    int row0 = tid >> 2;
    int col0 = (tid & 3) * 8;
    float2 mr0 = mursh[row0];
    float2 mr1 = mursh[row0 + 64];

    uint4 vA0 = *(const uint4*)(Ag + (size_t)row0*1024 + col0);
    uint4 vA1 = *(const uint4*)(Ag + (size_t)(row0+64)*1024 + col0);

    for (int k0 = 0; k0 < 1024; k0 += 32){
        // B staging for this iter (async)
        gload16(Bg + (size_t)row0*1024 + k0 + col0,       &Bsh[row0*32 + col0]);
        gload16(Bg + (size_t)(row0+64)*1024 + k0 + col0,  &Bsh[(row0+64)*32 + col0]);
        // transform current A regs (loaded last iter) -> As
        f32x4 sc0 = *(f32x4*)&scs[k0 + col0];
        f32x4 sc1 = *(f32x4*)&scs[k0 + col0 + 4];
        f32x4 bi0 = *(f32x4*)&bis[k0 + col0];
        f32x4 bi1 = *(f32x4*)&bis[k0 + col0 + 4];
        {
            const ushort* pv = (const ushort*)&vA0;
            ushort o[8];
            #pragma unroll
            for (int j = 0; j < 4; ++j){
                o[j]   = f2b((b2f(pv[j])   - mr0.x)*mr0.y*sc0[j] + bi0[j]);
                o[j+4] = f2b((b2f(pv[j+4]) - mr0.x)*mr0.y*sc1[j] + bi1[j]);
            }
            *(uint4*)&As[row0*32 + col0] = *(uint4*)&o[0];
        }
        {
            const ushort* pv = (const ushort*)&vA1;
            ushort o[8];
            #pragma unroll
            for (int j = 0; j < 4; ++j){
                o[j]   = f2b((b2f(pv[j])   - mr1.x)*mr1.y*sc0[j] + bi0[j]);
                o[j+4] = f2b((b2f(pv[j+4]) - mr1.x)*mr1.y*sc1[j] + bi1[j]);
            }
            *(uint4*)&As[(row0+64)*32 + col0] = *(uint4*)&o[0];
        }
        __syncthreads();
        // prefetch next iter's A regs — latency hides under the MFMAs below
        if (k0 + 32 < 1024){
            vA0 = *(const uint4*)(Ag + (size_t)row0*1024 + k0 + 32 + col0);
            vA1 = *(const uint4*)(Ag + (size_t)(row0+64)*1024 + k0 + 32 + col0);
        }
        bf16x8 af[4], bfr[4];
        #pragma unroll
        for (int i = 0; i < 4; ++i){
            int arow = wr*64 + i*16 + (lane & 15);
            af[i] = *(const bf16x8*)&As[arow*32 + ((lane >> 4) << 3)];
        }
        #pragma unroll
        for (int j = 0; j < 4; ++j){
            int brow = wc*64 + j*16 + (lane & 15);
            bfr[j] = *(const bf16x8*)&Bsh[brow*32 + ((lane >> 4) << 3)];
        }
        #pragma unroll
        for (int i = 0; i < 4; ++i)
            #pragma unroll
            for (int j = 0; j < 4; ++j)
                acc[i][j] = __builtin_amdgcn_mfma_f32_16x16x32_bf16(af[i], bfr[j], acc[i][j], 0, 0, 0);
        __syncthreads();
    }
    #pragma unroll
    for (int i = 0; i < 4; ++i){
        int m0 = bm*128 + wr*64 + i*16 + ((lane >> 4) << 2);
        #pragma unroll
        for (int j = 0; j < 4; ++j){
            int n = bn*128 + wc*64 + j*16 + (lane & 15);
            #pragma unroll
            for (int reg = 0; reg < 4; ++reg)
                Out[(size_t)(m0 + reg)*1024 + n] = acc[i][j][reg];
        }
    }
}

// ---------------------------------------------------------------------------
extern "C" void kernel_launch(void* const* d_in, const int* in_sizes, int n_in,
                              void* d_out, int out_size, void* d_ws, size_t ws_size,
                              hipStream_t stream){
    const float* X    = (const float*)d_in[0];
    const float* Bin  = (const float*)d_in[1];
    const float* Cin  = (const float*)d_in[2];
    const float* Wdt  = (const float*)d_in[3];
    const float* dtb  = (const float*)d_in[4];
    const float* alog = (const float*)d_in[5];
    const float* Wout = (const float*)d_in[6];
    const float* lns  = (const float*)d_in[7];
    const float* lnb  = (const float*)d_in[8];

    float* out = (float*)d_out;
    float* fs_out = out + (size_t)ROWS*DIM;

    char* ws = (char*)d_ws;
    float*  dt_t   = (float*)(ws);                         // 0.5 MB (transposed dt)
    float*  css_g  = (float*)(ws + 524288);                // 0.5 MB
    ushort* cstate = (ushort*)(ws + 1048576);              // 16 MB f16
    ushort* ybf    = (ushort*)(ws + 17825792);             // 16 MB bf16
    ushort* Wt     = (ushort*)(ws + 34603008);             // 2 MB  bf16

    k_dtwt <<<ROWS + 256,         256, 0, stream>>>(X, Wdt, dtb, Wout, dt_t, Wt);
    k_chunk<<<BATCH*NCHUNK*HEADS, 256, 0, stream>>>(X, Bin, Cin, dt_t, alog, ybf, cstate, css_g);
    k_scan <<<BATCH*HEADS*8,      256, 0, stream>>>(cstate, css_g, fs_out);
    k_yoff <<<BATCH*NCHUNK*HEADS, 256, 0, stream>>>(Cin, cstate, css_g, ybf);
    k_gemm <<<512,                256, 0, stream>>>(ybf, Wt, lns, lnb, out);
}

// Round 16
// 123.624 us; speedup vs baseline: 1.1581x; 1.1581x over previous
//
#include <hip/hip_runtime.h>
#include <hip/hip_bf16.h>
#include <hip/hip_fp16.h>
#include <math.h>

#define BATCH   2
#define SEQ     4096
#define DIM     1024
#define HEADS   16
#define DSTATE  64
#define HEADDIM 64
#define BLOCKL  64
#define NCHUNK  64
#define ROWS    (BATCH*SEQ)

typedef __attribute__((ext_vector_type(4))) float f32x4;
typedef __attribute__((ext_vector_type(8))) short bf16x8;
typedef __attribute__((ext_vector_type(8))) _Float16 f16x8;

static __device__ __forceinline__ float softplus_f(float x){
    return (x > 20.f) ? x : log1pf(__expf(x));
}
static __device__ __forceinline__ ushort f2b(float f){
    __hip_bfloat16 h = __float2bfloat16(f);
    return *reinterpret_cast<ushort*>(&h);
}
static __device__ __forceinline__ float b2f(ushort u){
    uint x = ((uint)u) << 16;
    return *reinterpret_cast<float*>(&x);
}
static __device__ __forceinline__ void gload16(const void* g, void* l){
    __builtin_amdgcn_global_load_lds((const __attribute__((address_space(1))) unsigned int*)g,
                                     (__attribute__((address_space(3))) unsigned int*)l, 16, 0, 0);
}

// ---------------------------------------------------------------------------
// K1 (merged): blocks [0,ROWS): dt per row (transposed dt_t[b*16+h][s]).
// blocks [ROWS,ROWS+256): Wt[n][k] = bf16(W_out[k][n])     (verified round 14)
__global__ __launch_bounds__(256) void k_dtwt(const float* __restrict__ X,
        const float* __restrict__ Wdt, const float* __restrict__ dtb,
        const float* __restrict__ W,
        float* __restrict__ dt_t, ushort* __restrict__ Wt){
    __shared__ float xrow[DIM];
    __shared__ float red[16][17];
    __shared__ float t[64][65];
    int bidx = blockIdx.x;
    int tid = threadIdx.x;
    if (bidx < ROWS){
        int r = bidx;
        int b = r >> 12;
        int s = r & (SEQ-1);
        *(f32x4*)(xrow + tid*4) = *(const f32x4*)(X + (size_t)r*DIM + tid*4);
        __syncthreads();
        int part = tid >> 4, h = tid & 15;
        int d0 = part * 64;
        float acc = 0.f;
        #pragma unroll 8
        for (int i = 0; i < 64; ++i)
            acc += xrow[d0 + i] * Wdt[(size_t)(d0 + i)*HEADS + h];
        red[part][h] = acc;
        __syncthreads();
        if (tid < 16){
            float sum = 0.f;
            #pragma unroll
            for (int p = 0; p < 16; ++p) sum += red[p][tid];
            sum += dtb[(size_t)s*HEADS + tid];
            float dtv = softplus_f(sum);
            dt_t[(size_t)(b*HEADS + tid)*SEQ + s] = dtv;
        }
    } else {
        int bid = bidx - ROWS;
        int kt = bid >> 4, nt = bid & 15;
        int lr = tid >> 4, lc4 = (tid & 15) * 4;
        #pragma unroll
        for (int q = 0; q < 4; ++q){
            int k = lr + q*16;
            *(f32x4*)&t[k][lc4] = *(const f32x4*)(W + (size_t)(kt*64 + k)*DIM + nt*64 + lc4);
        }
        __syncthreads();
        #pragma unroll
        for (int q = 0; q < 4; ++q){
            int n = lr + q*16;
            ushort o[4];
            #pragma unroll
            for (int j = 0; j < 4; ++j) o[j] = f2b(t[lc4+j][n]);
            *(short4*)(Wt + (size_t)(nt*64 + n)*DIM + kt*64 + lc4) = *(short4*)&o[0];
        }
    }
}

// ---------------------------------------------------------------------------
// K2 (MFMA): G=C·B^T -> M(bf16, own buffer) ; state = Xd^T·(w·B) ; Y_diag=M·Xd
// 4 barriers: {Cs|Bs} -> sync1 -> G -> sync2 -> {XdT|WBT scatter + Mb write}
// -> sync3 -> state MFMA + Y MFMA.  Per-wave redundant scan.
__global__ __launch_bounds__(256) void k_chunk(const float* __restrict__ X,
        const float* __restrict__ Bin, const float* __restrict__ Cin,
        const float* __restrict__ dt_t, const float* __restrict__ alog,
        ushort* __restrict__ ybf, ushort* __restrict__ cstate, float* __restrict__ css_g){
    int bid = blockIdx.x;                  // ((b*64+c)*16+h)
    int h = bid & 15, c = (bid >> 4) & 63, b = bid >> 10;
    int tid = threadIdx.x;
    int lane = tid & 63, wave = tid >> 6;
    int r0 = b*SEQ + c*BLOCKL;

    __shared__ __align__(16) char region0[18432];   // {Cs|Bs} -> {XdT|WBT}
    __shared__ __align__(16) ushort Mbuf[64*72];    // M (bf16), own region
    ushort* Cs  = (ushort*)region0;            // ph1 [64][72]
    ushort* Bs  = (ushort*)(region0 + 9216);   // ph1 [64][72]
    ushort* XdT = (ushort*)region0;            // ph2 (over Cs)
    ushort* WBT = (ushort*)(region0 + 9216);   // ph2 (over Bs)

    int l  = tid >> 2;
    int c0 = (tid & 3) * 16;

    f32x4 xr[4], br[4], cr[4];
    {
        const float* xp = X   + (size_t)(r0 + l)*DIM + h*HEADDIM + c0;
        const float* bp = Bin + (size_t)(r0 + l)*DIM + h*DSTATE  + c0;
        const float* cp = Cin + (size_t)(r0 + l)*DIM + h*DSTATE  + c0;
        #pragma unroll
        for (int q = 0; q < 4; ++q){
            xr[q] = *(const f32x4*)(xp + q*4);
            br[q] = *(const f32x4*)(bp + q*4);
            cr[q] = *(const f32x4*)(cp + q*4);
        }
    }
    float dt_l = dt_t[(size_t)(b*HEADS + h)*SEQ + c*BLOCKL + lane];
    float a    = -__expf(alog[h]) * dt_l;
    #pragma unroll
    for (int off = 1; off < 64; off <<= 1){
        float v = __shfl_up(a, off, 64);
        if (lane >= off) a += v;
    }
    float cs63 = __shfl(a, 63, 64);
    float w_l  = __expf(cs63 - a);
    if (tid < 64) css_g[(size_t)bid*64 + tid] = a;

    {
        ushort tc[16], tb[16];
        #pragma unroll
        for (int q = 0; q < 4; ++q)
            #pragma unroll
            for (int j = 0; j < 4; ++j){
                tc[q*4+j] = f2b(cr[q][j]);
                tb[q*4+j] = f2b(br[q][j]);
            }
        *(uint4*)&Cs[l*72 + c0]     = *(uint4*)&tc[0];
        *(uint4*)&Cs[l*72 + c0 + 8] = *(uint4*)&tc[8];
        *(uint4*)&Bs[l*72 + c0]     = *(uint4*)&tb[0];
        *(uint4*)&Bs[l*72 + c0 + 8] = *(uint4*)&tb[8];
    }
    __syncthreads();            // [sync1] Cs/Bs ready

    int cl15  = lane & 15;
    int g     = lane >> 4;
    int arow  = wave*16 + cl15;
    int kof   = g * 8;
    int rbase = wave*16 + g*4;

    // ---- G = C·B^T ---------------------------------------------------------
    f32x4 gacc[4];
    #pragma unroll
    for (int j = 0; j < 4; ++j) gacc[j] = (f32x4){0.f,0.f,0.f,0.f};
    #pragma unroll
    for (int k = 0; k < 2; ++k){
        bf16x8 aa = *(const bf16x8*)&Cs[arow*72 + k*32 + kof];
        #pragma unroll
        for (int j = 0; j < 4; ++j){
            bf16x8 bb = *(const bf16x8*)&Bs[(16*j + cl15)*72 + k*32 + kof];
            gacc[j] = __builtin_amdgcn_mfma_f32_16x16x32_bf16(aa, bb, gacc[j], 0, 0, 0);
        }
    }
    __syncthreads();            // [sync2] Cs/Bs dead -> XdT|WBT

    // scatter XdT/WBT (over region0) + M into Mbuf (register-only deps)
    {
        float dl = __shfl(dt_l, l, 64);
        float wl = __shfl(w_l,  l, 64);
        #pragma unroll
        for (int q = 0; q < 4; ++q)
            #pragma unroll
            for (int j = 0; j < 4; ++j){
                int p = c0 + q*4 + j;
                XdT[p*72 + l] = f2b(xr[q][j] * dl);
                WBT[p*72 + l] = f2b(br[q][j] * wl);
            }
    }
    {
        float csr[4], csc[4];
        #pragma unroll
        for (int r = 0; r < 4; ++r) csr[r] = __shfl(a, rbase + r, 64);
        #pragma unroll
        for (int j = 0; j < 4; ++j) csc[j] = __shfl(a, 16*j + cl15, 64);
        #pragma unroll
        for (int j = 0; j < 4; ++j)
            #pragma unroll
            for (int r = 0; r < 4; ++r){
                int row = rbase + r, col = 16*j + cl15;
                float m = (col <= row) ? gacc[j][r]*__expf(csr[r] - csc[j]) : 0.f;
                Mbuf[row*72 + col] = f2b(m);
            }
    }
    __syncthreads();            // [sync3] XdT/WBT/Mbuf ready

    // ---- chunk_state[p][n] = sum_l XdT[p][l] * WBT[n][l] --------------------
    f32x4 st[4];
    #pragma unroll
    for (int j = 0; j < 4; ++j) st[j] = (f32x4){0.f,0.f,0.f,0.f};
    #pragma unroll
    for (int k = 0; k < 2; ++k){
        bf16x8 aw = *(const bf16x8*)&XdT[arow*72 + k*32 + kof];
        #pragma unroll
        for (int j = 0; j < 4; ++j){
            bf16x8 bb = *(const bf16x8*)&WBT[(16*j + cl15)*72 + k*32 + kof];
            st[j] = __builtin_amdgcn_mfma_f32_16x16x32_bf16(aw, bb, st[j], 0, 0, 0);
        }
    }
    #pragma unroll
    for (int j = 0; j < 4; ++j)
        #pragma unroll
        for (int r = 0; r < 4; ++r){
            __half hv = __float2half(st[j][r]);
            cstate[(size_t)bid*4096 + (size_t)(rbase + r)*64 + 16*j + cl15] = *(ushort*)&hv;
        }

    // ---- Y_diag = M·Xd (bf16 store) -----------------------------------------
    f32x4 y[4];
    #pragma unroll
    for (int j = 0; j < 4; ++j) y[j] = (f32x4){0.f,0.f,0.f,0.f};
    #pragma unroll
    for (int k = 0; k < 2; ++k){
        bf16x8 am = *(const bf16x8*)&Mbuf[arow*72 + k*32 + kof];
        #pragma unroll
        for (int j = 0; j < 4; ++j){
            bf16x8 bx = *(const bf16x8*)&XdT[(16*j + cl15)*72 + k*32 + kof];
            y[j] = __builtin_amdgcn_mfma_f32_16x16x32_bf16(am, bx, y[j], 0, 0, 0);
        }
    }
    #pragma unroll
    for (int j = 0; j < 4; ++j)
        #pragma unroll
        for (int r = 0; r < 4; ++r)
            ybf[(size_t)(r0 + rbase + r)*DIM + h*HEADDIM + 16*j + cl15] = f2b(y[j][r]);
}

// ---------------------------------------------------------------------------
// K3: inter-chunk scan.  1 element/thread, 512 blocks (2 waves/SIMD TLP),
// decay factors in LDS, prefetch depth 2.  Same recurrence per element.
__global__ __launch_bounds__(256) void k_scan(ushort* __restrict__ cstate,
        const float* __restrict__ css_g, float* __restrict__ fs_out){
    int bid = blockIdx.x;                  // b(2) * h(16) * tile(16)
    int tile = bid & 15, hh = (bid >> 4) & 15, b = bid >> 8;
    int tid = threadIdx.x;
    int pn = tile*256 + tid;
    size_t base0 = (size_t)(b*NCHUNK)*HEADS + hh;
    __shared__ float esh[64];
    if (tid < 64)
        esh[tid] = __expf(css_g[(base0 + (size_t)tid*HEADS)*64 + 63]);
    __syncthreads();
    ushort* p0 = cstate + base0*4096 + pn;
    const size_t cstep = (size_t)HEADS*4096;
    float P = 0.f;
    __half cur = *(const __half*)p0;
    __half nxt = *(const __half*)(p0 + cstep);
    for (int c = 0; c < NCHUNK; ++c){
        __half fut = nxt;
        if (c + 2 < NCHUNK) fut = *(const __half*)(p0 + (size_t)(c+2)*cstep);
        *( __half*)(p0 + (size_t)c*cstep) = __float2half(P);
        P = esh[c]*P + __half2float(cur);
        cur = nxt;
        nxt = fut;
    }
    fs_out[(size_t)(b*HEADS + hh)*4096 + pn] = P;
}

// ---------------------------------------------------------------------------
// K4 (f16 MFMA): y += exp(cs[l]) * C·S^T  (bf16 RMW)   (verified round 10/14)
__global__ __launch_bounds__(256) void k_yoff(const float* __restrict__ Cin,
        const ushort* __restrict__ cstate, const float* __restrict__ css_g,
        ushort* __restrict__ ybf){
    int bid = blockIdx.x;
    int h = bid & 15, c = (bid >> 4) & 63, b = bid >> 10;
    int tid = threadIdx.x;
    int lane = tid & 63, wave = tid >> 6;
    int r0 = b*SEQ + c*BLOCKL;
    __shared__ __align__(16) ushort Cs[64*72];
    __shared__ __align__(16) ushort Ss[64*72];
    __shared__ float cse[64];
    {
        int l  = tid >> 2;
        int c0 = (tid & 3) * 16;
        const float* cp = Cin + (size_t)(r0 + l)*DIM + h*DSTATE + c0;
        ushort tc[16];
        #pragma unroll
        for (int q = 0; q < 4; ++q){
            f32x4 vc = *(const f32x4*)(cp + q*4);
            #pragma unroll
            for (int j = 0; j < 4; ++j){
                __half hv = __float2half(vc[j]);
                tc[q*4+j] = *(ushort*)&hv;
            }
        }
        *(uint4*)&Cs[l*72 + c0]     = *(uint4*)&tc[0];
        *(uint4*)&Cs[l*72 + c0 + 8] = *(uint4*)&tc[8];
        const ushort* sp = cstate + (size_t)bid*4096 + (size_t)l*64 + c0;
        *(uint4*)&Ss[l*72 + c0]     = *(const uint4*)sp;
        *(uint4*)&Ss[l*72 + c0 + 8] = *(const uint4*)(sp + 8);
    }
    if (tid < 64) cse[tid] = __expf(css_g[(size_t)bid*64 + tid]);
    __syncthreads();

    int cl15 = lane & 15;
    int g    = lane >> 4;
    int arow = wave*16 + cl15;
    int kof  = g * 8;
    f32x4 acc[4];
    #pragma unroll
    for (int j = 0; j < 4; ++j) acc[j] = (f32x4){0.f,0.f,0.f,0.f};
    #pragma unroll
    for (int k = 0; k < 2; ++k){
        f16x8 a = *(const f16x8*)&Cs[arow*72 + k*32 + kof];
        #pragma unroll
        for (int j = 0; j < 4; ++j){
            f16x8 bb = *(const f16x8*)&Ss[(16*j + cl15)*72 + k*32 + kof];
            acc[j] = __builtin_amdgcn_mfma_f32_16x16x32_f16(a, bb, acc[j], 0, 0, 0);
        }
    }
    int rbase = wave*16 + g*4;
    #pragma unroll
    for (int j = 0; j < 4; ++j)
        #pragma unroll
        for (int r = 0; r < 4; ++r){
            float e = cse[rbase + r];
            size_t idx = (size_t)(r0 + rbase + r)*DIM + h*HEADDIM + 16*j + cl15;
            ybf[idx] = f2b(b2f(ybf[idx]) + e * acc[j][r]);
        }
}

// ---------------------------------------------------------------------------
// K5: LayerNorm over dim (bf16 in, bf16 out, in-place)   (verified round 10/14)
__global__ __launch_bounds__(256) void k_ln(ushort* __restrict__ ybf,
        const float* __restrict__ scale, const float* __restrict__ bias){
    int r = blockIdx.x, tid = threadIdx.x;
    ushort* yp = ybf + (size_t)r*DIM + tid*4;
    short4 raw = *(const short4*)yp;
    float v[4];
    v[0] = b2f((ushort)raw.x); v[1] = b2f((ushort)raw.y);
    v[2] = b2f((ushort)raw.z); v[3] = b2f((ushort)raw.w);
    float s1 = v[0]+v[1]+v[2]+v[3];
    float s2 = v[0]*v[0]+v[1]*v[1]+v[2]*v[2]+v[3]*v[3];
    #pragma unroll
    for (int m = 32; m > 0; m >>= 1){
        s1 += __shfl_xor(s1, m, 64);
        s2 += __shfl_xor(s2, m, 64);
    }
    __shared__ float w1[4], w2[4];
    int wv = tid >> 6;
    if ((tid & 63) == 0){ w1[wv] = s1; w2[wv] = s2; }
    __syncthreads();
    float S1 = w1[0]+w1[1]+w1[2]+w1[3];
    float S2 = w2[0]+w2[1]+w2[2]+w2[3];
    float mu  = S1 * (1.f/DIM);
    float var = S2 * (1.f/DIM) - mu*mu;
    float rstd = rsqrtf(var + 1e-6f);
    int d = tid*4;
    f32x4 sc = *(const f32x4*)(scale + d);
    f32x4 bi = *(const f32x4*)(bias + d);
    ushort o[4];
    #pragma unroll
    for (int j = 0; j < 4; ++j)
        o[j] = f2b((v[j] - mu)*rstd*sc[j] + bi[j]);
    *(short4*)yp = *(short4*)&o[0];
}

// ---------------------------------------------------------------------------
// K6: Out = yn @ Wt^T.  128x128 tile, grid 512, gload16 + XCD swizzle.
// (verified rounds 8/9/14 — the fold variants are permanently abandoned)
__global__ __launch_bounds__(256) void k_gemm(const ushort* __restrict__ A,
        const ushort* __restrict__ Bt, float* __restrict__ Out){
    __shared__ __align__(16) ushort As[128*32];
    __shared__ __align__(16) ushort Bsh[128*32];
    int bid = blockIdx.x;
    int wgid = (bid & 7)*64 + (bid >> 3);      // XCD swizzle (512 = 8 XCD * 64)
    int bn = wgid & 7, bm = wgid >> 3;
    int tid = threadIdx.x;
    int lane = tid & 63, wave = tid >> 6;
    int wr = wave >> 1, wc = wave & 1;
    f32x4 acc[4][4];
    #pragma unroll
    for (int i = 0; i < 4; ++i)
        #pragma unroll
        for (int j = 0; j < 4; ++j)
            acc[i][j] = (f32x4){0.f, 0.f, 0.f, 0.f};
    const ushort* Ag = A  + (size_t)bm*128*1024;
    const ushort* Bg = Bt + (size_t)bn*128*1024;
    int row0 = tid >> 2;
    int col0 = (tid & 3) * 8;
    for (int k0 = 0; k0 < 1024; k0 += 32){
        const ushort* sA = Ag + (size_t)row0*1024 + k0 + col0;
        const ushort* sB = Bg + (size_t)row0*1024 + k0 + col0;
        gload16(sA,           &As[row0*32 + col0]);
        gload16(sA + 64*1024, &As[(row0+64)*32 + col0]);
        gload16(sB,           &Bsh[row0*32 + col0]);
        gload16(sB + 64*1024, &Bsh[(row0+64)*32 + col0]);
        __syncthreads();
        bf16x8 af[4], bfr[4];
        #pragma unroll
        for (int i = 0; i < 4; ++i){
            int arow = wr*64 + i*16 + (lane & 15);
            af[i] = *(const bf16x8*)&As[arow*32 + ((lane >> 4) << 3)];
        }
        #pragma unroll
        for (int j = 0; j < 4; ++j){
            int brow = wc*64 + j*16 + (lane & 15);
            bfr[j] = *(const bf16x8*)&Bsh[brow*32 + ((lane >> 4) << 3)];
        }
        #pragma unroll
        for (int i = 0; i < 4; ++i)
            #pragma unroll
            for (int j = 0; j < 4; ++j)
                acc[i][j] = __builtin_amdgcn_mfma_f32_16x16x32_bf16(af[i], bfr[j], acc[i][j], 0, 0, 0);
        __syncthreads();
    }
    #pragma unroll
    for (int i = 0; i < 4; ++i){
        int m0 = bm*128 + wr*64 + i*16 + ((lane >> 4) << 2);
        #pragma unroll
        for (int j = 0; j < 4; ++j){
            int n = bn*128 + wc*64 + j*16 + (lane & 15);
            #pragma unroll
            for (int reg = 0; reg < 4; ++reg)
                Out[(size_t)(m0 + reg)*1024 + n] = acc[i][j][reg];
        }
    }
}

// ---------------------------------------------------------------------------
extern "C" void kernel_launch(void* const* d_in, const int* in_sizes, int n_in,
                              void* d_out, int out_size, void* d_ws, size_t ws_size,
                              hipStream_t stream){
    const float* X    = (const float*)d_in[0];
    const float* Bin  = (const float*)d_in[1];
    const float* Cin  = (const float*)d_in[2];
    const float* Wdt  = (const float*)d_in[3];
    const float* dtb  = (const float*)d_in[4];
    const float* alog = (const float*)d_in[5];
    const float* Wout = (const float*)d_in[6];
    const float* lns  = (const float*)d_in[7];
    const float* lnb  = (const float*)d_in[8];

    float* out = (float*)d_out;
    float* fs_out = out + (size_t)ROWS*DIM;

    char* ws = (char*)d_ws;
    float*  dt_t   = (float*)(ws);                         // 0.5 MB (transposed dt)
    float*  css_g  = (float*)(ws + 524288);                // 0.5 MB
    ushort* cstate = (ushort*)(ws + 1048576);              // 16 MB f16
    ushort* ybf    = (ushort*)(ws + 17825792);             // 16 MB bf16 (y -> yn in place)
    ushort* Wt     = (ushort*)(ws + 34603008);             // 2 MB  bf16

    k_dtwt <<<ROWS + 256,         256, 0, stream>>>(X, Wdt, dtb, Wout, dt_t, Wt);
    k_chunk<<<BATCH*NCHUNK*HEADS, 256, 0, stream>>>(X, Bin, Cin, dt_t, alog, ybf, cstate, css_g);
    k_scan <<<BATCH*HEADS*16,     256, 0, stream>>>(cstate, css_g, fs_out);
    k_yoff <<<BATCH*NCHUNK*HEADS, 256, 0, stream>>>(Cin, cstate, css_g, ybf);
    k_ln   <<<ROWS,               256, 0, stream>>>(ybf, lns, lnb);
    k_gemm <<<512,                256, 0, stream>>>(ybf, Wt, out);
}

// Round 17
// 120.926 us; speedup vs baseline: 1.1840x; 1.0223x over previous
//
#include <hip/hip_runtime.h>
#include <hip/hip_bf16.h>
#include <hip/hip_fp16.h>
#include <math.h>

#define BATCH   2
#define SEQ     4096
#define DIM     1024
#define HEADS   16
#define DSTATE  64
#define HEADDIM 64
#define BLOCKL  64
#define NCHUNK  64
#define ROWS    (BATCH*SEQ)

typedef __attribute__((ext_vector_type(4))) float f32x4;
typedef __attribute__((ext_vector_type(8))) short bf16x8;
typedef __attribute__((ext_vector_type(8))) _Float16 f16x8;

static __device__ __forceinline__ float softplus_f(float x){
    return (x > 20.f) ? x : log1pf(__expf(x));
}
static __device__ __forceinline__ ushort f2b(float f){
    __hip_bfloat16 h = __float2bfloat16(f);
    return *reinterpret_cast<ushort*>(&h);
}
static __device__ __forceinline__ float b2f(ushort u){
    uint x = ((uint)u) << 16;
    return *reinterpret_cast<float*>(&x);
}
static __device__ __forceinline__ void gload16(const void* g, void* l){
    __builtin_amdgcn_global_load_lds((const __attribute__((address_space(1))) unsigned int*)g,
                                     (__attribute__((address_space(3))) unsigned int*)l, 16, 0, 0);
}

// ---------------------------------------------------------------------------
// K1 (merged): blocks [0,ROWS): dt per row (TRANSPOSED layout dt_t[b*16+h][s]).
// blocks [ROWS,ROWS+256): Wt[n][k] = bf16(W_out[k][n])
__global__ __launch_bounds__(256) void k_dtwt(const float* __restrict__ X,
        const float* __restrict__ Wdt, const float* __restrict__ dtb,
        const float* __restrict__ W,
        float* __restrict__ dt_t, ushort* __restrict__ Wt){
    __shared__ float xrow[DIM];
    __shared__ float red[16][17];
    __shared__ float t[64][65];
    int bidx = blockIdx.x;
    int tid = threadIdx.x;
    if (bidx < ROWS){
        int r = bidx;
        int b = r >> 12;              // r / SEQ
        int s = r & (SEQ-1);
        *(f32x4*)(xrow + tid*4) = *(const f32x4*)(X + (size_t)r*DIM + tid*4);
        __syncthreads();
        int part = tid >> 4, h = tid & 15;
        int d0 = part * 64;
        float acc = 0.f;
        #pragma unroll 8
        for (int i = 0; i < 64; ++i)
            acc += xrow[d0 + i] * Wdt[(size_t)(d0 + i)*HEADS + h];
        red[part][h] = acc;
        __syncthreads();
        if (tid < 16){
            float sum = 0.f;
            #pragma unroll
            for (int p = 0; p < 16; ++p) sum += red[p][tid];
            sum += dtb[(size_t)s*HEADS + tid];
            float dtv = softplus_f(sum);
            dt_t[(size_t)(b*HEADS + tid)*SEQ + s] = dtv;   // transposed; L2 merges
        }
    } else {
        int bid = bidx - ROWS;
        int kt = bid >> 4, nt = bid & 15;
        int lr = tid >> 4, lc4 = (tid & 15) * 4;
        #pragma unroll
        for (int q = 0; q < 4; ++q){
            int k = lr + q*16;
            *(f32x4*)&t[k][lc4] = *(const f32x4*)(W + (size_t)(kt*64 + k)*DIM + nt*64 + lc4);
        }
        __syncthreads();
        #pragma unroll
        for (int q = 0; q < 4; ++q){
            int n = lr + q*16;
            ushort o[4];
            #pragma unroll
            for (int j = 0; j < 4; ++j) o[j] = f2b(t[lc4+j][n]);
            *(short4*)(Wt + (size_t)(nt*64 + n)*DIM + kt*64 + lc4) = *(short4*)&o[0];
        }
    }
}

// ---------------------------------------------------------------------------
// K2 (MFMA): G=C·B^T -> M(bf16) ; state = Xd^T·(w·B) ; Y_diag=M·Xd (bf16 out)
// LDS 18 KB, triple-overlaid; per-wave redundant scan; dtA computed inline.
__global__ __launch_bounds__(256) void k_chunk(const float* __restrict__ X,
        const float* __restrict__ Bin, const float* __restrict__ Cin,
        const float* __restrict__ dt_t, const float* __restrict__ alog,
        ushort* __restrict__ ybf, ushort* __restrict__ cstate, float* __restrict__ css_g){
    int bid = blockIdx.x;                  // ((b*64+c)*16+h)
    int h = bid & 15, c = (bid >> 4) & 63, b = bid >> 10;
    int tid = threadIdx.x;
    int lane = tid & 63, wave = tid >> 6;
    int r0 = b*SEQ + c*BLOCKL;

    __shared__ __align__(16) char region0[18432];
    ushort* Cs  = (ushort*)region0;            // ph1 [64][72]
    ushort* Bs  = (ushort*)(region0 + 9216);   // ph1 [64][72]
    ushort* XdT = (ushort*)region0;            // ph2/3 (over Cs)
    ushort* WBT = (ushort*)(region0 + 9216);   // ph2   (over Bs)
    ushort* Mb  = (ushort*)(region0 + 9216);   // ph3   (over WBT)

    int l  = tid >> 2;
    int c0 = (tid & 3) * 16;

    f32x4 xr[4], br[4], cr[4];
    {
        const float* xp = X   + (size_t)(r0 + l)*DIM + h*HEADDIM + c0;
        const float* bp = Bin + (size_t)(r0 + l)*DIM + h*DSTATE  + c0;
        const float* cp = Cin + (size_t)(r0 + l)*DIM + h*DSTATE  + c0;
        #pragma unroll
        for (int q = 0; q < 4; ++q){
            xr[q] = *(const f32x4*)(xp + q*4);
            br[q] = *(const f32x4*)(bp + q*4);
            cr[q] = *(const f32x4*)(cp + q*4);
        }
    }
    // coalesced transposed dt read + inline dtA; per-wave redundant scan
    float dt_l = dt_t[(size_t)(b*HEADS + h)*SEQ + c*BLOCKL + lane];
    float a    = -__expf(alog[h]) * dt_l;
    #pragma unroll
    for (int off = 1; off < 64; off <<= 1){
        float v = __shfl_up(a, off, 64);
        if (lane >= off) a += v;
    }
    float cs63 = __shfl(a, 63, 64);
    float w_l  = __expf(cs63 - a);
    if (tid < 64) css_g[(size_t)bid*64 + tid] = a;

    {
        ushort tc[16], tb[16];
        #pragma unroll
        for (int q = 0; q < 4; ++q)
            #pragma unroll
            for (int j = 0; j < 4; ++j){
                tc[q*4+j] = f2b(cr[q][j]);
                tb[q*4+j] = f2b(br[q][j]);
            }
        *(uint4*)&Cs[l*72 + c0]     = *(uint4*)&tc[0];
        *(uint4*)&Cs[l*72 + c0 + 8] = *(uint4*)&tc[8];
        *(uint4*)&Bs[l*72 + c0]     = *(uint4*)&tb[0];
        *(uint4*)&Bs[l*72 + c0 + 8] = *(uint4*)&tb[8];
    }
    __syncthreads();            // [sync1]

    int cl15  = lane & 15;
    int g     = lane >> 4;
    int arow  = wave*16 + cl15;
    int kof   = g * 8;
    int rbase = wave*16 + g*4;

    f32x4 gacc[4];
    #pragma unroll
    for (int j = 0; j < 4; ++j) gacc[j] = (f32x4){0.f,0.f,0.f,0.f};
    #pragma unroll
    for (int k = 0; k < 2; ++k){
        bf16x8 aa = *(const bf16x8*)&Cs[arow*72 + k*32 + kof];
        #pragma unroll
        for (int j = 0; j < 4; ++j){
            bf16x8 bb = *(const bf16x8*)&Bs[(16*j + cl15)*72 + k*32 + kof];
            gacc[j] = __builtin_amdgcn_mfma_f32_16x16x32_bf16(aa, bb, gacc[j], 0, 0, 0);
        }
    }
    __syncthreads();            // [sync2]

    {
        float dl = __shfl(dt_l, l, 64);
        float wl = __shfl(w_l,  l, 64);
        #pragma unroll
        for (int q = 0; q < 4; ++q)
            #pragma unroll
            for (int j = 0; j < 4; ++j){
                int p = c0 + q*4 + j;
                XdT[p*72 + l] = f2b(xr[q][j] * dl);
                WBT[p*72 + l] = f2b(br[q][j] * wl);
            }
    }
    __syncthreads();            // [sync3]

    f32x4 st[4];
    #pragma unroll
    for (int j = 0; j < 4; ++j) st[j] = (f32x4){0.f,0.f,0.f,0.f};
    #pragma unroll
    for (int k = 0; k < 2; ++k){
        bf16x8 aw = *(const bf16x8*)&XdT[arow*72 + k*32 + kof];
        #pragma unroll
        for (int j = 0; j < 4; ++j){
            bf16x8 bb = *(const bf16x8*)&WBT[(16*j + cl15)*72 + k*32 + kof];
            st[j] = __builtin_amdgcn_mfma_f32_16x16x32_bf16(aw, bb, st[j], 0, 0, 0);
        }
    }
    #pragma unroll
    for (int j = 0; j < 4; ++j)
        #pragma unroll
        for (int r = 0; r < 4; ++r){
            __half hv = __float2half(st[j][r]);
            cstate[(size_t)bid*4096 + (size_t)(rbase + r)*64 + 16*j + cl15] = *(ushort*)&hv;
        }

    float mreg[4][4];
    {
        float csr[4], csc[4];
        #pragma unroll
        for (int r = 0; r < 4; ++r) csr[r] = __shfl(a, rbase + r, 64);
        #pragma unroll
        for (int j = 0; j < 4; ++j) csc[j] = __shfl(a, 16*j + cl15, 64);
        #pragma unroll
        for (int j = 0; j < 4; ++j)
            #pragma unroll
            for (int r = 0; r < 4; ++r){
                int row = rbase + r, col = 16*j + cl15;
                mreg[j][r] = (col <= row) ? gacc[j][r]*__expf(csr[r] - csc[j]) : 0.f;
            }
    }
    __syncthreads();            // [sync4]

    #pragma unroll
    for (int j = 0; j < 4; ++j)
        #pragma unroll
        for (int r = 0; r < 4; ++r)
            Mb[(rbase + r)*72 + 16*j + cl15] = f2b(mreg[j][r]);
    __syncthreads();            // [sync5]

    f32x4 y[4];
    #pragma unroll
    for (int j = 0; j < 4; ++j) y[j] = (f32x4){0.f,0.f,0.f,0.f};
    #pragma unroll
    for (int k = 0; k < 2; ++k){
        bf16x8 am = *(const bf16x8*)&Mb[arow*72 + k*32 + kof];
        #pragma unroll
        for (int j = 0; j < 4; ++j){
            bf16x8 bx = *(const bf16x8*)&XdT[(16*j + cl15)*72 + k*32 + kof];
            y[j] = __builtin_amdgcn_mfma_f32_16x16x32_bf16(am, bx, y[j], 0, 0, 0);
        }
    }
    #pragma unroll
    for (int j = 0; j < 4; ++j)
        #pragma unroll
        for (int r = 0; r < 4; ++r)
            ybf[(size_t)(r0 + rbase + r)*DIM + h*HEADDIM + 16*j + cl15] = f2b(y[j][r]);
}

// ---------------------------------------------------------------------------
// K3: inter-chunk scan. Decay factors preloaded to LDS; prefetch depth 2.
__global__ __launch_bounds__(256) void k_scan(ushort* __restrict__ cstate,
        const float* __restrict__ css_g, float* __restrict__ fs_out){
    int bid = blockIdx.x;                  // b(2) * h(16) * tile(8)
    int tile = bid & 7, hh = (bid >> 3) & 15, b = bid >> 7;
    int tid = threadIdx.x;
    int pn = tile*512 + tid*2;
    size_t base0 = (size_t)(b*NCHUNK)*HEADS + hh;
    __shared__ float esh[64];
    if (tid < 64)
        esh[tid] = __expf(css_g[(base0 + (size_t)tid*HEADS)*64 + 63]);
    __syncthreads();
    ushort* p0 = cstate + base0*4096 + pn;
    const size_t cstep = (size_t)HEADS*4096;
    float P0 = 0.f, P1 = 0.f;
    __half2 cur = *(const __half2*)p0;
    __half2 nxt = *(const __half2*)(p0 + cstep);
    for (int c = 0; c < NCHUNK; ++c){
        __half2 fut = nxt;
        if (c + 2 < NCHUNK) fut = *(const __half2*)(p0 + (size_t)(c+2)*cstep);
        *( __half2*)(p0 + (size_t)c*cstep) = __floats2half2_rn(P0, P1);
        float2 cf = __half22float2(cur);
        float e = esh[c];
        P0 = e*P0 + cf.x;
        P1 = e*P1 + cf.y;
        cur = nxt;
        nxt = fut;
    }
    *(float2*)&fs_out[(size_t)(b*HEADS + hh)*4096 + pn] = make_float2(P0, P1);
}

// ---------------------------------------------------------------------------
// K4 (f16 MFMA): y += exp(cs[l]) * C·S^T  (bf16 RMW)   (verified round 10/14)
__global__ __launch_bounds__(256) void k_yoff(const float* __restrict__ Cin,
        const ushort* __restrict__ cstate, const float* __restrict__ css_g,
        ushort* __restrict__ ybf){
    int bid = blockIdx.x;
    int h = bid & 15, c = (bid >> 4) & 63, b = bid >> 10;
    int tid = threadIdx.x;
    int lane = tid & 63, wave = tid >> 6;
    int r0 = b*SEQ + c*BLOCKL;
    __shared__ __align__(16) ushort Cs[64*72];
    __shared__ __align__(16) ushort Ss[64*72];
    __shared__ float cse[64];
    {
        int l  = tid >> 2;
        int c0 = (tid & 3) * 16;
        const float* cp = Cin + (size_t)(r0 + l)*DIM + h*DSTATE + c0;
        ushort tc[16];
        #pragma unroll
        for (int q = 0; q < 4; ++q){
            f32x4 vc = *(const f32x4*)(cp + q*4);
            #pragma unroll
            for (int j = 0; j < 4; ++j){
                __half hv = __float2half(vc[j]);
                tc[q*4+j] = *(ushort*)&hv;
            }
        }
        *(uint4*)&Cs[l*72 + c0]     = *(uint4*)&tc[0];
        *(uint4*)&Cs[l*72 + c0 + 8] = *(uint4*)&tc[8];
        const ushort* sp = cstate + (size_t)bid*4096 + (size_t)l*64 + c0;
        *(uint4*)&Ss[l*72 + c0]     = *(const uint4*)sp;
        *(uint4*)&Ss[l*72 + c0 + 8] = *(const uint4*)(sp + 8);
    }
    if (tid < 64) cse[tid] = __expf(css_g[(size_t)bid*64 + tid]);
    __syncthreads();

    int cl15 = lane & 15;
    int g    = lane >> 4;
    int arow = wave*16 + cl15;
    int kof  = g * 8;
    f32x4 acc[4];
    #pragma unroll
    for (int j = 0; j < 4; ++j) acc[j] = (f32x4){0.f,0.f,0.f,0.f};
    #pragma unroll
    for (int k = 0; k < 2; ++k){
        f16x8 a = *(const f16x8*)&Cs[arow*72 + k*32 + kof];
        #pragma unroll
        for (int j = 0; j < 4; ++j){
            f16x8 bb = *(const f16x8*)&Ss[(16*j + cl15)*72 + k*32 + kof];
            acc[j] = __builtin_amdgcn_mfma_f32_16x16x32_f16(a, bb, acc[j], 0, 0, 0);
        }
    }
    int rbase = wave*16 + g*4;
    #pragma unroll
    for (int j = 0; j < 4; ++j)
        #pragma unroll
        for (int r = 0; r < 4; ++r){
            float e = cse[rbase + r];
            size_t idx = (size_t)(r0 + rbase + r)*DIM + h*HEADDIM + 16*j + cl15;
            ybf[idx] = f2b(b2f(ybf[idx]) + e * acc[j][r]);
        }
}

// ---------------------------------------------------------------------------
// K5: LayerNorm over dim (bf16 in, bf16 out, in-place)   (verified round 10)
__global__ __launch_bounds__(256) void k_ln(ushort* __restrict__ ybf,
        const float* __restrict__ scale, const float* __restrict__ bias){
    int r = blockIdx.x, tid = threadIdx.x;
    ushort* yp = ybf + (size_t)r*DIM + tid*4;
    short4 raw = *(const short4*)yp;
    float v[4];
    v[0] = b2f((ushort)raw.x); v[1] = b2f((ushort)raw.y);
    v[2] = b2f((ushort)raw.z); v[3] = b2f((ushort)raw.w);
    float s1 = v[0]+v[1]+v[2]+v[3];
    float s2 = v[0]*v[0]+v[1]*v[1]+v[2]*v[2]+v[3]*v[3];
    #pragma unroll
    for (int m = 32; m > 0; m >>= 1){
        s1 += __shfl_xor(s1, m, 64);
        s2 += __shfl_xor(s2, m, 64);
    }
    __shared__ float w1[4], w2[4];
    int wv = tid >> 6;
    if ((tid & 63) == 0){ w1[wv] = s1; w2[wv] = s2; }
    __syncthreads();
    float S1 = w1[0]+w1[1]+w1[2]+w1[3];
    float S2 = w2[0]+w2[1]+w2[2]+w2[3];
    float mu  = S1 * (1.f/DIM);
    float var = S2 * (1.f/DIM) - mu*mu;
    float rstd = rsqrtf(var + 1e-6f);
    int d = tid*4;
    f32x4 sc = *(const f32x4*)(scale + d);
    f32x4 bi = *(const f32x4*)(bias + d);
    ushort o[4];
    #pragma unroll
    for (int j = 0; j < 4; ++j)
        o[j] = f2b((v[j] - mu)*rstd*sc[j] + bi[j]);
    *(short4*)yp = *(short4*)&o[0];
}

// ---------------------------------------------------------------------------
// K6: Out = yn @ Wt^T.  128x128 tile, grid 512, gload16 + XCD swizzle.
__global__ __launch_bounds__(256) void k_gemm(const ushort* __restrict__ A,
        const ushort* __restrict__ Bt, float* __restrict__ Out){
    __shared__ __align__(16) ushort As[128*32];
    __shared__ __align__(16) ushort Bsh[128*32];
    int bid = blockIdx.x;
    int wgid = (bid & 7)*64 + (bid >> 3);      // XCD swizzle (512 = 8 XCD * 64)
    int bn = wgid & 7, bm = wgid >> 3;
    int tid = threadIdx.x;
    int lane = tid & 63, wave = tid >> 6;
    int wr = wave >> 1, wc = wave & 1;
    f32x4 acc[4][4];
    #pragma unroll
    for (int i = 0; i < 4; ++i)
        #pragma unroll
        for (int j = 0; j < 4; ++j)
            acc[i][j] = (f32x4){0.f, 0.f, 0.f, 0.f};
    const ushort* Ag = A  + (size_t)bm*128*1024;
    const ushort* Bg = Bt + (size_t)bn*128*1024;
    int row0 = tid >> 2;
    int col0 = (tid & 3) * 8;
    for (int k0 = 0; k0 < 1024; k0 += 32){
        const ushort* sA = Ag + (size_t)row0*1024 + k0 + col0;
        const ushort* sB = Bg + (size_t)row0*1024 + k0 + col0;
        gload16(sA,           &As[row0*32 + col0]);
        gload16(sA + 64*1024, &As[(row0+64)*32 + col0]);
        gload16(sB,           &Bsh[row0*32 + col0]);
        gload16(sB + 64*1024, &Bsh[(row0+64)*32 + col0]);
        __syncthreads();
        bf16x8 af[4], bfr[4];
        #pragma unroll
        for (int i = 0; i < 4; ++i){
            int arow = wr*64 + i*16 + (lane & 15);
            af[i] = *(const bf16x8*)&As[arow*32 + ((lane >> 4) << 3)];
        }
        #pragma unroll
        for (int j = 0; j < 4; ++j){
            int brow = wc*64 + j*16 + (lane & 15);
            bfr[j] = *(const bf16x8*)&Bsh[brow*32 + ((lane >> 4) << 3)];
        }
        #pragma unroll
        for (int i = 0; i < 4; ++i)
            #pragma unroll
            for (int j = 0; j < 4; ++j)
                acc[i][j] = __builtin_amdgcn_mfma_f32_16x16x32_bf16(af[i], bfr[j], acc[i][j], 0, 0, 0);
        __syncthreads();
    }
    #pragma unroll
    for (int i = 0; i < 4; ++i){
        int m0 = bm*128 + wr*64 + i*16 + ((lane >> 4) << 2);
        #pragma unroll
        for (int j = 0; j < 4; ++j){
            int n = bn*128 + wc*64 + j*16 + (lane & 15);
            #pragma unroll
            for (int reg = 0; reg < 4; ++reg)
                Out[(size_t)(m0 + reg)*1024 + n] = acc[i][j][reg];
        }
    }
}

// ---------------------------------------------------------------------------
extern "C" void kernel_launch(void* const* d_in, const int* in_sizes, int n_in,
                              void* d_out, int out_size, void* d_ws, size_t ws_size,
                              hipStream_t stream){
    const float* X    = (const float*)d_in[0];
    const float* Bin  = (const float*)d_in[1];
    const float* Cin  = (const float*)d_in[2];
    const float* Wdt  = (const float*)d_in[3];
    const float* dtb  = (const float*)d_in[4];
    const float* alog = (const float*)d_in[5];
    const float* Wout = (const float*)d_in[6];
    const float* lns  = (const float*)d_in[7];
    const float* lnb  = (const float*)d_in[8];

    float* out = (float*)d_out;
    float* fs_out = out + (size_t)ROWS*DIM;

    char* ws = (char*)d_ws;
    float*  dt_t   = (float*)(ws);                         // 0.5 MB (transposed dt)
    float*  css_g  = (float*)(ws + 524288);                // 0.5 MB
    ushort* cstate = (ushort*)(ws + 1048576);              // 16 MB f16
    ushort* ybf    = (ushort*)(ws + 17825792);             // 16 MB bf16 (y -> yn in place)
    ushort* Wt     = (ushort*)(ws + 34603008);             // 2 MB  bf16

    k_dtwt <<<ROWS + 256,         256, 0, stream>>>(X, Wdt, dtb, Wout, dt_t, Wt);
    k_chunk<<<BATCH*NCHUNK*HEADS, 256, 0, stream>>>(X, Bin, Cin, dt_t, alog, ybf, cstate, css_g);
    k_scan <<<BATCH*HEADS*8,      256, 0, stream>>>(cstate, css_g, fs_out);
    k_yoff <<<BATCH*NCHUNK*HEADS, 256, 0, stream>>>(Cin, cstate, css_g, ybf);
    k_ln   <<<ROWS,               256, 0, stream>>>(ybf, lns, lnb);
    k_gemm <<<512,                256, 0, stream>>>(ybf, Wt, out);
}